// Round 14
// baseline (1449.387 us; speedup 1.0000x reference)
//
#include <hip/hip_runtime.h>
#include <math.h>

#define B_ 4
#define D_ 768
#define NH_ 12
#define HD_ 64
#define FF_ 3072
#define L_ 256
#define PD_ 768
#define GRID_ 16
#define P_ 16
#define IMG_ 256
#define M_ (B_*L_)                 // 1024 rows
#define NCONV_ (B_*128*IMG_*IMG_)  // 33554432

typedef __attribute__((ext_vector_type(8))) short short8;
typedef __attribute__((ext_vector_type(4))) float f32x4;
typedef __attribute__((ext_vector_type(4))) unsigned short us4;
typedef __attribute__((ext_vector_type(8))) unsigned short us8;
typedef unsigned short ushort_t;

__device__ __forceinline__ float mishf(float x){
    float e = __expf(x);
    float u = (1.f + e) * (1.f + e);
    return x * (1.f - 2.f / (u + 1.f));
}

__device__ __forceinline__ int refl(int i, int n){
    if (i < 0) i = -i;
    if (i >= n) i = 2*n - 2 - i;
    return i;
}

__device__ __forceinline__ ushort_t f2bf(float f){
    unsigned int u = __float_as_uint(f);
    unsigned int r = (u + 0x7FFFu + ((u >> 16) & 1u)) >> 16;
    return (ushort_t)r;
}
__device__ __forceinline__ float bf2f(ushort_t u){
    return __uint_as_float(((unsigned int)u) << 16);
}

// async global->LDS, 16B per lane; lds dest must be wave-uniform (HW adds lane*16)
__device__ __forceinline__ void gl16(const void* g, void* l){
    __builtin_amdgcn_global_load_lds(
        (const __attribute__((address_space(1))) unsigned int*)g,
        (__attribute__((address_space(3))) unsigned int*)l, 16, 0, 0);
}

__device__ __forceinline__ void block_red2(float& s, float& q){
    #pragma unroll
    for (int o = 32; o > 0; o >>= 1){ s += __shfl_down(s, o); q += __shfl_down(q, o); }
    __shared__ float r1[4], r2[4];
    int tid = threadIdx.x;
    if ((tid & 63) == 0){ r1[tid>>6] = s; r2[tid>>6] = q; }
    __syncthreads();
    if (tid == 0){ s = r1[0]+r1[1]+r1[2]+r1[3]; q = r2[0]+r2[1]+r2[2]+r2[3]; }
    __syncthreads();
}

// ---------------- patchify
__global__ __launch_bounds__(256) void k_patchify(const float* __restrict__ x, float* __restrict__ t){
    int idx = blockIdx.x*256 + threadIdx.x;
    int d = idx % PD_; int l = (idx/PD_) % L_; int b = idx/(PD_*L_);
    int c = d % 3; int p = d / 3; int p1 = p / P_; int p2 = p % P_;
    int gh = l / GRID_; int gw = l % GRID_;
    int sy = gh*P_ + p1, sx = gw*P_ + p2;
    t[idx] = x[(((size_t)b*3 + c)*IMG_ + sy)*IMG_ + sx];
}

// ---------------- weight transpose+convert: W[K][N] f32 -> Wt[N][K] bf16
__global__ __launch_bounds__(256) void k_wt(const float* __restrict__ b0, const float* __restrict__ b1,
                                            const float* __restrict__ b2, int n0, int n1,
                                            ushort_t* __restrict__ dst, int K, int N){
    int z = blockIdx.z;
    size_t sz = (size_t)K * N;
    const float* src = (z < n0) ? b0 + (size_t)z*sz
                     : (z < n0+n1) ? b1 + (size_t)(z-n0)*sz
                     : b2 + (size_t)(z-n0-n1)*sz;
    ushort_t* out = dst + (size_t)z*sz;
    __shared__ float ld[32][33];
    int k0 = blockIdx.y*32, nc0 = blockIdx.x*32;
    int tid = threadIdx.x;
    int c = tid & 31, r8 = tid >> 5;
    #pragma unroll
    for (int i = 0; i < 4; ++i){
        int k = r8 + i*8;
        ld[k][c] = src[(size_t)(k0+k)*N + nc0 + c];
    }
    __syncthreads();
    #pragma unroll
    for (int i = 0; i < 4; ++i){
        int n = r8 + i*8;
        out[(size_t)(nc0+n)*K + k0 + c] = f2bf(ld[c][n]);
    }
}

// ---------------- RMSNorm
template<bool OUT_BF>
__global__ __launch_bounds__(256) void k_rms(const float* __restrict__ x, const float* __restrict__ w,
                                             const float* __restrict__ addv, void* __restrict__ yv){
    int row = blockIdx.x;
    const float* xr = x + (size_t)row * D_;
    float s = 0.f;
    for (int i = threadIdx.x; i < D_; i += 256){ float v = xr[i]; s += v*v; }
    __shared__ float red[256];
    red[threadIdx.x] = s; __syncthreads();
    for (int o = 128; o > 0; o >>= 1){
        if (threadIdx.x < o) red[threadIdx.x] += red[threadIdx.x+o];
        __syncthreads();
    }
    float rstd = rsqrtf(red[0]/(float)D_ + 1e-5f);
    int l = row % L_;
    for (int i = threadIdx.x; i < D_; i += 256){
        float v = xr[i]*rstd*w[i];
        if (addv) v += addv[(size_t)l*D_ + i];
        if (OUT_BF) ((ushort_t*)yv)[(size_t)row*D_ + i] = f2bf(v);
        else        ((float*)yv)[(size_t)row*D_ + i] = v;
    }
}

// ---------------- fused split-K(2) reduce + residual + (optional) next RMSNorm
__global__ __launch_bounds__(256) void k_skred_rms(const float* __restrict__ Pp, float* __restrict__ t,
                                                   const float* __restrict__ w, ushort_t* __restrict__ nb){
    int row = blockIdx.x;
    int tid = threadIdx.x;
    float v[3];
    float s = 0.f;
    #pragma unroll
    for (int i = 0; i < 3; ++i){
        int c = tid + i*256;
        size_t o = (size_t)row*D_ + c;
        float x = t[o] + Pp[o] + Pp[(size_t)M_*D_ + o];
        v[i] = x; s += x*x;
        t[o] = x;
    }
    #pragma unroll
    for (int o = 32; o > 0; o >>= 1) s += __shfl_down(s, o);
    __shared__ float r1[4];
    if ((tid & 63) == 0) r1[tid>>6] = s;
    __syncthreads();
    float tot = r1[0]+r1[1]+r1[2]+r1[3];
    float rstd = rsqrtf(tot*(1.f/768.f) + 1e-5f);
    if (w){
        #pragma unroll
        for (int i = 0; i < 3; ++i){
            int c = tid + i*256;
            nb[(size_t)row*D_ + c] = f2bf(v[i]*rstd*w[c]);
        }
    }
}

// ---------------- bf16 MFMA GEMM 64x64, BK=64, double-buffered global_load_lds staging.
// One barrier per K-step: stage next tile right after barrier, MFMA on current.
template<bool OBF, int SPLITK>
__global__ __launch_bounds__(256) void k_gemm(const ushort_t* __restrict__ A, const ushort_t* __restrict__ Wt,
                                              void* __restrict__ Cv, const float* __restrict__ bias,
                                              const float* __restrict__ res, int N, int K){
    __shared__ ushort_t As[2][2][64][32];   // [dbuf][kchunk][row][k]
    __shared__ ushort_t Ws[2][2][64][32];
    int tid = threadIdx.x;
    int lane = tid & 63, wid = tid >> 6;
    int wr = wid >> 1, wc = wid & 1;
    int row0 = blockIdx.y * 64, col0 = blockIdx.x * 64;
    f32x4 acc[2][2];
    #pragma unroll
    for (int i = 0; i < 2; ++i)
        #pragma unroll
        for (int j = 0; j < 2; ++j) acc[i][j] = (f32x4){0.f,0.f,0.f,0.f};

    int lg = lane >> 4, lr = lane & 15;
    int kc = K / SPLITK;
    int k0 = (SPLITK > 1) ? blockIdx.z * kc : 0;
    int srow = wid*16 + (lane >> 2);
    int scol = (lane & 3) * 8;
    const ushort_t* gA = A  + (size_t)(row0 + srow)*K + k0 + scol;
    const ushort_t* gW = Wt + (size_t)(col0 + srow)*K + k0 + scol;

    // prologue: stage tile 0 into buffer 0
    gl16(gA,      &As[0][0][wid*16][0]);
    gl16(gA + 32, &As[0][1][wid*16][0]);
    gl16(gW,      &Ws[0][0][wid*16][0]);
    gl16(gW + 32, &Ws[0][1][wid*16][0]);
    int cur = 0;

    for (int kt = 0; kt < kc; kt += 64){
        __syncthreads();    // drains loads into buf[cur]; prev reads of buf[cur^1] done
        if (kt + 64 < kc){
            gl16(gA + kt + 64, &As[cur^1][0][wid*16][0]);
            gl16(gA + kt + 96, &As[cur^1][1][wid*16][0]);
            gl16(gW + kt + 64, &Ws[cur^1][0][wid*16][0]);
            gl16(gW + kt + 96, &Ws[cur^1][1][wid*16][0]);
        }
        short8 a0[2], a1[2], b0[2], b1[2];
        #pragma unroll
        for (int i = 0; i < 2; ++i){
            a0[i] = *(const short8*)(&As[cur][0][wr*32 + i*16 + lr][lg*8]);
            a1[i] = *(const short8*)(&As[cur][1][wr*32 + i*16 + lr][lg*8]);
        }
        #pragma unroll
        for (int j = 0; j < 2; ++j){
            b0[j] = *(const short8*)(&Ws[cur][0][wc*32 + j*16 + lr][lg*8]);
            b1[j] = *(const short8*)(&Ws[cur][1][wc*32 + j*16 + lr][lg*8]);
        }
        #pragma unroll
        for (int i = 0; i < 2; ++i)
            #pragma unroll
            for (int j = 0; j < 2; ++j){
                acc[i][j] = __builtin_amdgcn_mfma_f32_16x16x32_bf16(a0[i], b0[j], acc[i][j], 0, 0, 0);
                acc[i][j] = __builtin_amdgcn_mfma_f32_16x16x32_bf16(a1[i], b1[j], acc[i][j], 0, 0, 0);
            }
        cur ^= 1;
    }
    if (SPLITK > 1){
        float* Pp = (float*)Cv + (size_t)blockIdx.z * M_ * N;
        #pragma unroll
        for (int i = 0; i < 2; ++i)
            #pragma unroll
            for (int j = 0; j < 2; ++j)
                #pragma unroll
                for (int q = 0; q < 4; ++q){
                    int m = row0 + wr*32 + i*16 + lg*4 + q;
                    int n = col0 + wc*32 + j*16 + lr;
                    Pp[(size_t)m*N + n] = acc[i][j][q];
                }
    } else {
        #pragma unroll
        for (int i = 0; i < 2; ++i)
            #pragma unroll
            for (int j = 0; j < 2; ++j)
                #pragma unroll
                for (int q = 0; q < 4; ++q){
                    int m = row0 + wr*32 + i*16 + lg*4 + q;
                    int n = col0 + wc*32 + j*16 + lr;
                    float v = acc[i][j][q];
                    if (bias) v += bias[n];
                    size_t o = (size_t)m*N + n;
                    if (OBF){
                        ((ushort_t*)Cv)[o] = f2bf(v);
                    } else {
                        if (res) v += res[o];
                        ((float*)Cv)[o] = v;
                    }
                }
    }
}

// ---------------- ff1 GEMM with fused mish-GLU epilogue, BK=32 double-buffered.
__global__ __launch_bounds__(256) void k_gemm_glu(const ushort_t* __restrict__ A, const ushort_t* __restrict__ Wt,
                                                  ushort_t* __restrict__ Cb, int K){
    __shared__ ushort_t As[2][64][32];
    __shared__ ushort_t Wa[2][64][32];
    __shared__ ushort_t Wg[2][64][32];
    int tid = threadIdx.x;
    int lane = tid & 63, wid = tid >> 6;
    int wr = wid >> 1, wc = wid & 1;
    int row0 = blockIdx.y * 64, col0 = blockIdx.x * 64;
    f32x4 aa[2][2], ag[2][2];
    #pragma unroll
    for (int i = 0; i < 2; ++i)
        #pragma unroll
        for (int j = 0; j < 2; ++j){ aa[i][j] = (f32x4){0.f,0.f,0.f,0.f}; ag[i][j] = (f32x4){0.f,0.f,0.f,0.f}; }

    int lg = lane >> 4, lr = lane & 15;
    int srow = wid*16 + (lane >> 2);
    int scol = (lane & 3) * 8;
    const ushort_t* gA  = A  + (size_t)(row0 + srow)*K + scol;
    const ushort_t* gWa = Wt + (size_t)(col0 + srow)*K + scol;
    const ushort_t* gWg = Wt + (size_t)(FF_ + col0 + srow)*K + scol;

    gl16(gA,  &As[0][wid*16][0]);
    gl16(gWa, &Wa[0][wid*16][0]);
    gl16(gWg, &Wg[0][wid*16][0]);
    int cur = 0;

    for (int kt = 0; kt < K; kt += 32){
        __syncthreads();
        if (kt + 32 < K){
            gl16(gA  + kt + 32, &As[cur^1][wid*16][0]);
            gl16(gWa + kt + 32, &Wa[cur^1][wid*16][0]);
            gl16(gWg + kt + 32, &Wg[cur^1][wid*16][0]);
        }
        short8 a[2], ba[2], bg[2];
        #pragma unroll
        for (int i = 0; i < 2; ++i) a[i] = *(const short8*)(&As[cur][wr*32 + i*16 + lr][lg*8]);
        #pragma unroll
        for (int j = 0; j < 2; ++j){
            ba[j] = *(const short8*)(&Wa[cur][wc*32 + j*16 + lr][lg*8]);
            bg[j] = *(const short8*)(&Wg[cur][wc*32 + j*16 + lr][lg*8]);
        }
        #pragma unroll
        for (int i = 0; i < 2; ++i)
            #pragma unroll
            for (int j = 0; j < 2; ++j){
                aa[i][j] = __builtin_amdgcn_mfma_f32_16x16x32_bf16(a[i], ba[j], aa[i][j], 0, 0, 0);
                ag[i][j] = __builtin_amdgcn_mfma_f32_16x16x32_bf16(a[i], bg[j], ag[i][j], 0, 0, 0);
            }
        cur ^= 1;
    }
    #pragma unroll
    for (int i = 0; i < 2; ++i)
        #pragma unroll
        for (int j = 0; j < 2; ++j)
            #pragma unroll
            for (int q = 0; q < 4; ++q){
                int m = row0 + wr*32 + i*16 + lg*4 + q;
                int n = col0 + wc*32 + j*16 + lr;
                Cb[(size_t)m*FF_ + n] = f2bf(mishf(aa[i][j][q]) * ag[i][j][q]);
            }
}

// ---------------- MFMA attention (unchanged, verified)
__global__ __launch_bounds__(256) void k_attn(const ushort_t* __restrict__ qkv, ushort_t* __restrict__ out){
    int qt = blockIdx.x, h = blockIdx.y, b = blockIdx.z;
    const ushort_t* base = qkv + (size_t)b * L_ * 3 * D_;
    __shared__ ushort_t Qs[64][72];
    __shared__ ushort_t KVs[64][72];
    __shared__ ushort_t Ps[64][268];
    __shared__ float red[8][64];
    int tid = threadIdx.x;
    int lane = tid & 63, w = tid >> 6;
    int lr = lane & 15, lg = lane >> 4;

    {
        int r = tid >> 2, c = (tid & 3) * 16;
        const ushort_t* src = base + (size_t)(qt*64 + r)*3*D_ + h*HD_ + c;
        *(us8*)&Qs[r][c]   = *(const us8*)src;
        *(us8*)&Qs[r][c+8] = *(const us8*)(src + 8);
    }

    f32x4 sacc[4][4];
    #pragma unroll
    for (int kt = 0; kt < 4; ++kt)
        #pragma unroll
        for (int mi = 0; mi < 4; ++mi) sacc[kt][mi] = (f32x4){0.f,0.f,0.f,0.f};

    for (int kt = 0; kt < 4; ++kt){
        __syncthreads();
        {
            int r = tid >> 2, c = (tid & 3) * 16;
            const ushort_t* src = base + (size_t)(kt*64 + r)*3*D_ + D_ + h*HD_ + c;
            *(us8*)&KVs[r][c]   = *(const us8*)src;
            *(us8*)&KVs[r][c+8] = *(const us8*)(src + 8);
        }
        __syncthreads();
        short8 bk0 = *(const short8*)&KVs[w*16 + lr][lg*8];
        short8 bk1 = *(const short8*)&KVs[w*16 + lr][32 + lg*8];
        #pragma unroll
        for (int mi = 0; mi < 4; ++mi){
            short8 a0 = *(const short8*)&Qs[mi*16 + lr][lg*8];
            short8 a1 = *(const short8*)&Qs[mi*16 + lr][32 + lg*8];
            sacc[kt][mi] = __builtin_amdgcn_mfma_f32_16x16x32_bf16(a0, bk0, sacc[kt][mi], 0, 0, 0);
            sacc[kt][mi] = __builtin_amdgcn_mfma_f32_16x16x32_bf16(a1, bk1, sacc[kt][mi], 0, 0, 0);
        }
    }

    const float inv64 = 1.0f/64.0f;
    float gm[4][4], linv[4][4];
    #pragma unroll
    for (int mi = 0; mi < 4; ++mi){
        #pragma unroll
        for (int r = 0; r < 4; ++r){
            float v = fmaxf(fmaxf(sacc[0][mi][r], sacc[1][mi][r]), fmaxf(sacc[2][mi][r], sacc[3][mi][r]));
            v = fmaxf(v, __shfl_xor(v, 1));
            v = fmaxf(v, __shfl_xor(v, 2));
            v = fmaxf(v, __shfl_xor(v, 4));
            v = fmaxf(v, __shfl_xor(v, 8));
            gm[mi][r] = v;
            if (lr == 0) red[w][mi*16 + lg*4 + r] = v;
        }
    }
    __syncthreads();
    #pragma unroll
    for (int mi = 0; mi < 4; ++mi){
        #pragma unroll
        for (int r = 0; r < 4; ++r){
            int row = mi*16 + lg*4 + r;
            float m = fmaxf(fmaxf(red[0][row], red[1][row]), fmaxf(red[2][row], red[3][row]));
            gm[mi][r] = m;
            float sum = 0.f;
            #pragma unroll
            for (int kt = 0; kt < 4; ++kt){
                float p = __expf((sacc[kt][mi][r] - m) * inv64);
                Ps[row][kt*64 + w*16 + lr] = f2bf(p);
                sum += p;
            }
            sum += __shfl_xor(sum, 1);
            sum += __shfl_xor(sum, 2);
            sum += __shfl_xor(sum, 4);
            sum += __shfl_xor(sum, 8);
            linv[mi][r] = sum;
            if (lr == 0) red[4 + w][row] = sum;
        }
    }
    __syncthreads();
    #pragma unroll
    for (int mi = 0; mi < 4; ++mi){
        #pragma unroll
        for (int r = 0; r < 4; ++r){
            int row = mi*16 + lg*4 + r;
            linv[mi][r] = 1.0f / (red[4][row] + red[5][row] + red[6][row] + red[7][row]);
        }
    }

    f32x4 oacc[4];
    #pragma unroll
    for (int mi = 0; mi < 4; ++mi) oacc[mi] = (f32x4){0.f,0.f,0.f,0.f};
    for (int kt = 0; kt < 4; ++kt){
        __syncthreads();
        {
            int k = tid & 63, dg = tid >> 6;
            const ushort_t* src = base + (size_t)(kt*64 + k)*3*D_ + 2*D_ + h*HD_ + dg*16;
            us8 v0 = *(const us8*)src;
            us8 v1 = *(const us8*)(src + 8);
            #pragma unroll
            for (int j = 0; j < 8; ++j) KVs[dg*16 + j][k] = v0[j];
            #pragma unroll
            for (int j = 0; j < 8; ++j) KVs[dg*16 + 8 + j][k] = v1[j];
        }
        __syncthreads();
        short8 bv0 = *(const short8*)&KVs[w*16 + lr][lg*8];
        short8 bv1 = *(const short8*)&KVs[w*16 + lr][32 + lg*8];
        #pragma unroll
        for (int mi = 0; mi < 4; ++mi){
            short8 a0 = *(const short8*)&Ps[mi*16 + lr][kt*64 + lg*8];
            short8 a1 = *(const short8*)&Ps[mi*16 + lr][kt*64 + 32 + lg*8];
            oacc[mi] = __builtin_amdgcn_mfma_f32_16x16x32_bf16(a0, bv0, oacc[mi], 0, 0, 0);
            oacc[mi] = __builtin_amdgcn_mfma_f32_16x16x32_bf16(a1, bv1, oacc[mi], 0, 0, 0);
        }
    }
    #pragma unroll
    for (int mi = 0; mi < 4; ++mi){
        #pragma unroll
        for (int r = 0; r < 4; ++r){
            int row = mi*16 + lg*4 + r;
            out[((size_t)(b*L_ + qt*64 + row))*D_ + h*HD_ + w*16 + lr] = f2bf(oacc[mi][r] * linv[mi][r]);
        }
    }
}

// ---------------- concat convert
__global__ __launch_bounds__(256) void k_cat(const float* __restrict__ t, const float* __restrict__ skip,
                                             ushort_t* __restrict__ cat){
    int i4 = (blockIdx.x*256 + threadIdx.x) * 4;
    int r = i4 / D_, c = i4 % D_;
    float4 a = *(const float4*)(t + i4);
    float4 b = *(const float4*)(skip + i4);
    us4 ua, ub;
    ua.x=f2bf(a.x); ua.y=f2bf(a.y); ua.z=f2bf(a.z); ua.w=f2bf(a.w);
    ub.x=f2bf(b.x); ub.y=f2bf(b.y); ub.z=f2bf(b.z); ub.w=f2bf(b.w);
    *(us4*)(cat + (size_t)r*1536 + c) = ua;
    *(us4*)(cat + (size_t)r*1536 + 768 + c) = ub;
}

// ---------------- unpatchify
__global__ __launch_bounds__(256) void k_unpatchify(const float* __restrict__ t, float* __restrict__ img){
    int idx = blockIdx.x*256 + threadIdx.x;
    int sx = idx % IMG_; int sy = (idx/IMG_)%IMG_; int c = (idx/(IMG_*IMG_))%3; int b = idx/(3*IMG_*IMG_);
    int gh = sy / P_, p1 = sy % P_, gw = sx / P_, p2 = sx % P_;
    img[idx] = t[(((size_t)b*L_) + gh*GRID_+gw)*PD_ + (p1*P_+p2)*3 + c];
}

// ---------------- conv_in: 3->128, 3x3 reflect. block=(y, ocg, b); 32 oc per block.
__global__ __launch_bounds__(256) void k_conv_in(const float* __restrict__ img, const float* __restrict__ w,
                                                 ushort_t* __restrict__ out, float* __restrict__ partial){
    int y = blockIdx.x, ocg = blockIdx.y, b = blockIdx.z;
    int x = threadIdx.x;
    __shared__ float rows[9][IMG_];
    int yy0 = refl(y-1, IMG_), yy2 = refl(y+1, IMG_);
    #pragma unroll
    for (int ic = 0; ic < 3; ++ic){
        const float* basep = img + ((size_t)(b*3+ic))*IMG_*IMG_;
        rows[ic*3+0][x] = basep[(size_t)yy0*IMG_ + x];
        rows[ic*3+1][x] = basep[(size_t)y  *IMG_ + x];
        rows[ic*3+2][x] = basep[(size_t)yy2*IMG_ + x];
    }
    __syncthreads();
    int xl = (x==0)?1:x-1, xr = (x==255)?254:x+1;
    float sg = 0.f, qg = 0.f;
    for (int oc = ocg*32; oc < ocg*32 + 32; ++oc){
        const float* wv = w + oc*27;
        float acc = 0.f;
        #pragma unroll
        for (int ic = 0; ic < 3; ++ic){
            const float* wk = wv + ic*9;
            acc += rows[ic*3+0][xl]*wk[0] + rows[ic*3+0][x]*wk[1] + rows[ic*3+0][xr]*wk[2]
                 + rows[ic*3+1][xl]*wk[3] + rows[ic*3+1][x]*wk[4] + rows[ic*3+1][xr]*wk[5]
                 + rows[ic*3+2][xl]*wk[6] + rows[ic*3+2][x]*wk[7] + rows[ic*3+2][xr]*wk[8];
        }
        out[(((size_t)(b*128+oc))*IMG_ + y)*IMG_ + x] = f2bf(acc);
        sg += acc; qg += acc*acc;
        if ((oc & 15) == 15){
            block_red2(sg, qg);
            if (threadIdx.x == 0){
                int pidx = ((b*8 + (oc>>4))*256 + y);
                partial[pidx*2] = sg; partial[pidx*2+1] = qg;
            }
            sg = 0.f; qg = 0.f;
        }
    }
}

// ---------------- stats finish: 32 groups
__global__ __launch_bounds__(256) void k_gn_fin(const float* __restrict__ partial, int nper,
                                                float* __restrict__ stats){
    int bg = blockIdx.x, tid = threadIdx.x;
    float s = 0.f, q = 0.f;
    for (int i = tid; i < nper; i += 256){
        s += partial[((size_t)bg*nper + i)*2];
        q += partial[((size_t)bg*nper + i)*2 + 1];
    }
    block_red2(s, q);
    if (tid == 0){
        const float n = 16.f*IMG_*IMG_;
        float m = s/n;
        float var = q/n - m*m;
        stats[bg*2]   = m;
        stats[bg*2+1] = rsqrtf(var + 1e-5f);
    }
}

// ---------------- activation pass: y = mish(gn(x)) bf16
__global__ __launch_bounds__(256) void k_act(const ushort_t* __restrict__ x, const float* __restrict__ st,
                                             const float* __restrict__ gw, const float* __restrict__ gb,
                                             ushort_t* __restrict__ y){
    int bid = blockIdx.x;
    int b = bid >> 11, c = (bid >> 4) & 127;
    int bg = b*8 + (c>>4);
    float sc = st[bg*2+1]*gw[c], sb = gb[c] - st[bg*2]*sc;
    size_t e0 = (size_t)bid*4096 + threadIdx.x*16;
    us8 v0 = *(const us8*)(x + e0), v1 = *(const us8*)(x + e0 + 8);
    us8 r0, r1;
    #pragma unroll
    for (int i = 0; i < 8; ++i) r0[i] = f2bf(mishf(bf2f(v0[i])*sc + sb));
    #pragma unroll
    for (int i = 0; i < 8; ++i) r1[i] = f2bf(mishf(bf2f(v1[i])*sc + sb));
    *(us8*)(y + e0) = r0;
    *(us8*)(y + e0 + 8) = r1;
}

// ---------------- depthwise 5x5 pure conv (measured-best: strides 40/48, pre-activated input)
template<int PAD, int DIL>
__global__ __launch_bounds__(256) void k_dw(const ushort_t* __restrict__ in,
                                            const float* __restrict__ cw,
                                            ushort_t* __restrict__ out, float* __restrict__ partial){
    constexpr int AP = (DIL==1) ? 4 : 8;
    constexpr int SC = (DIL==1) ? 40 : 48;
    constexpr int SY = 64 + 2*PAD;
    constexpr int CH = SC/4;
    __shared__ float tile[SY*SC];
    int tileid = blockIdx.x, c = blockIdx.y, b = blockIdx.z;
    int x0 = (tileid & 7) * 32, y0 = (tileid >> 3) * 64;
    int tid = threadIdx.x;
    const ushort_t* ip = in + ((size_t)(b*128+c))*IMG_*IMG_;
    int xs = x0 - AP;
    if (xs >= 0 && xs + SC <= IMG_){
        for (int j = tid; j < SY*CH; j += 256){
            int r = j / CH, q = j - r*CH;
            int gy = refl(y0 - PAD + r, IMG_);
            us4 v = *(const us4*)(ip + (size_t)gy*IMG_ + xs + q*4);
            f32x4 fv = { bf2f(v.x), bf2f(v.y), bf2f(v.z), bf2f(v.w) };
            *(f32x4*)&tile[r*SC + q*4] = fv;
        }
    } else {
        for (int j = tid; j < SY*SC; j += 256){
            int r = j / SC, cc = j - r*SC;
            int gy = refl(y0 - PAD + r, IMG_);
            int gx = refl(xs + cc, IMG_);
            tile[r*SC + cc] = bf2f(ip[(size_t)gy*IMG_ + gx]);
        }
    }
    __syncthreads();
    float wreg[25];
    #pragma unroll
    for (int u = 0; u < 25; ++u) wreg[u] = cw[c*25 + u];
    int tx4 = (tid & 7)*4, ty = tid >> 3;
    constexpr int NV = (DIL==1) ? 3 : 5;
    float s = 0.f, q2 = 0.f;
    #pragma unroll
    for (int rr = 0; rr < 2; ++rr){
        int yy = ty + rr*32;
        float acc[4] = {0.f,0.f,0.f,0.f};
        #pragma unroll
        for (int kh = 0; kh < 5; ++kh){
            const float* rowp = &tile[(yy + kh*DIL)*SC + tx4];
            float vv[NV*4];
            #pragma unroll
            for (int u = 0; u < NV; ++u){
                f32x4 v = *(const f32x4*)(rowp + u*4);
                vv[u*4]=v.x; vv[u*4+1]=v.y; vv[u*4+2]=v.z; vv[u*4+3]=v.w;
            }
            #pragma unroll
            for (int kw = 0; kw < 5; ++kw){
                float wk = wreg[kh*5+kw];
                #pragma unroll
                for (int j = 0; j < 4; ++j)
                    acc[j] += vv[kw*DIL + j + (AP - 2*DIL)] * wk;
            }
        }
        us4 o4 = { f2bf(acc[0]), f2bf(acc[1]), f2bf(acc[2]), f2bf(acc[3]) };
        *(us4*)(out + (((size_t)(b*128+c))*IMG_ + y0+yy)*IMG_ + x0+tx4) = o4;
        s  += acc[0]+acc[1]+acc[2]+acc[3];
        q2 += acc[0]*acc[0]+acc[1]*acc[1]+acc[2]*acc[2]+acc[3]*acc[3];
    }
    block_red2(s, q2);
    if (tid == 0){
        int bid = (b*128 + c)*32 + tileid;
        partial[bid*2] = s; partial[bid*2+1] = q2;
    }
}

// ---------------- fused residual: out = mish(gn_n(xn)) + res_act (pre-activated residual)
__global__ __launch_bounds__(256) void k_addmish(const ushort_t* __restrict__ xn, const float* __restrict__ stn,
                                                 const float* __restrict__ wn, const float* __restrict__ bn,
                                                 const ushort_t* __restrict__ resa,
                                                 ushort_t* __restrict__ out, float* __restrict__ partial){
    int bid = blockIdx.x;
    int b = bid >> 11, c = (bid >> 4) & 127;
    int bg = b*8 + (c>>4);
    float scn = stn[bg*2+1]*wn[c], sbn = bn[c] - stn[bg*2]*scn;
    size_t e0 = (size_t)bid*4096 + threadIdx.x*16;
    us8 vn0 = *(const us8*)(xn + e0), vn1 = *(const us8*)(xn + e0 + 8);
    us8 vr0 = *(const us8*)(resa + e0), vr1 = *(const us8*)(resa + e0 + 8);
    us8 r0, r1;
    float s = 0.f, q = 0.f;
    #pragma unroll
    for (int i = 0; i < 8; ++i){
        float v = mishf(bf2f(vn0[i])*scn + sbn) + bf2f(vr0[i]);
        s += v; q += v*v; r0[i] = f2bf(v);
    }
    #pragma unroll
    for (int i = 0; i < 8; ++i){
        float v = mishf(bf2f(vn1[i])*scn + sbn) + bf2f(vr1[i]);
        s += v; q += v*v; r1[i] = f2bf(v);
    }
    *(us8*)(out + e0) = r0;
    *(us8*)(out + e0 + 8) = r1;
    block_red2(s, q);
    if (threadIdx.x == 0){ partial[bid*2] = s; partial[bid*2+1] = q; }
}

// ---------------- head conv part (unchanged)
__global__ __launch_bounds__(256) void k_head_part(const ushort_t* __restrict__ in, const float* __restrict__ st,
                                                   const float* __restrict__ gw, const float* __restrict__ gb,
                                                   const float* __restrict__ w, float* __restrict__ part){
    __shared__ float tile[34*34];
    int tileid = blockIdx.x, cg = blockIdx.y, b = blockIdx.z;
    int x0 = (tileid & 7)*32, y0 = (tileid >> 3)*32;
    int tid = threadIdx.x;
    int tx4 = (tid & 7)*4, ty = tid >> 3;
    float m  = st[(b*8+cg)*2];
    float rs = st[(b*8+cg)*2 + 1];
    float acc[4] = {0.f,0.f,0.f,0.f};
    for (int ci = 0; ci < 16; ++ci){
        int c = cg*16 + ci;
        float sc = rs*gw[c], sb = gb[c] - m*sc;
        const ushort_t* ip = in + ((size_t)(b*128+c))*IMG_*IMG_;
        if (ci) __syncthreads();
        for (int i = tid; i < 34*34; i += 256){
            int r = i/34, cc = i - r*34;
            int gy = refl(y0-1+r, IMG_);
            int gx = refl(x0-1+cc, IMG_);
            tile[i] = mishf(bf2f(ip[(size_t)gy*IMG_+gx])*sc + sb);
        }
        __syncthreads();
        const float* wc = w + c*9;
        #pragma unroll
        for (int kh = 0; kh < 3; ++kh){
            float vv[6];
            #pragma unroll
            for (int u = 0; u < 6; ++u) vv[u] = tile[(ty+kh)*34 + tx4 + u];
            #pragma unroll
            for (int kw = 0; kw < 3; ++kw){
                float wk = wc[kh*3+kw];
                #pragma unroll
                for (int j = 0; j < 4; ++j) acc[j] += vv[kw+j]*wk;
            }
        }
    }
    f32x4 o = {acc[0], acc[1], acc[2], acc[3]};
    *(f32x4*)(part + (((size_t)(cg*4+b))*IMG_ + y0+ty)*IMG_ + x0+tx4) = o;
}

__global__ __launch_bounds__(256) void k_head_fin(const float* __restrict__ part, float* __restrict__ out){
    int idx4 = blockIdx.x*256 + threadIdx.x;
    size_t e = (size_t)idx4*4;
    int b = (int)(e / (IMG_*IMG_));
    size_t off = e % (IMG_*IMG_);
    f32x4 s = {0.f,0.f,0.f,0.f};
    #pragma unroll
    for (int cg = 0; cg < 8; ++cg){
        f32x4 v = *(const f32x4*)(part + (size_t)(cg*4+b)*IMG_*IMG_ + off);
        s.x += v.x; s.y += v.y; s.z += v.z; s.w += v.w;
    }
    *(f32x4*)(out + e) = s;
}

// =======================================================================

struct WsMap {
    float *t, *skip, *t2, *ybuf, *img, *partial, *hpart, *stats, *part;
    ushort_t *nb, *qkvb, *ab, *gbuf, *cat, *wb_qkv, *wb_out, *wb_w1, *wb_w2, *wb_pe, *wb_skip, *wb_ol, *cA, *cB;
};

// Assumes W.nb already holds rms(t, this_attn_norm) bf16.
static void run_block(const float* fn, const ushort_t* qw, const ushort_t* ow,
                      const ushort_t* w1, const ushort_t* w2, const float* next_w,
                      float* t, const WsMap& W, hipStream_t stream){
    k_gemm<true,1><<<dim3(3*D_/64, M_/64), 256, 0, stream>>>(W.nb, qw, W.qkvb, nullptr, nullptr, 3*D_, D_);
    k_attn<<<dim3(4, NH_, B_), 256, 0, stream>>>(W.qkvb, W.ab);
    k_gemm<false,2><<<dim3(D_/64, M_/64, 2), 256, 0, stream>>>(W.ab, ow, W.part, nullptr, nullptr, D_, D_);
    k_skred_rms<<<M_, 256, 0, stream>>>(W.part, t, fn, W.nb);
    k_gemm_glu<<<dim3(FF_/64, M_/64), 256, 0, stream>>>(W.nb, w1, W.gbuf, D_);
    k_gemm<false,2><<<dim3(D_/64, M_/64, 2), 256, 0, stream>>>(W.gbuf, w2, W.part, nullptr, nullptr, D_, FF_);
    k_skred_rms<<<M_, 256, 0, stream>>>(W.part, t, next_w, W.nb);
}

extern "C" void kernel_launch(void* const* d_in, const int* in_sizes, int n_in,
                              void* d_out, int out_size, void* d_ws, size_t ws_size,
                              hipStream_t stream){
    const float* x              = (const float*)d_in[0];
    const float* pe_norm_w      = (const float*)d_in[1];
    const float* pe_proj_w      = (const float*)d_in[2];
    const float* pe_proj_b      = (const float*)d_in[3];
    const float* pe_norm_out_w  = (const float*)d_in[4];
    const float* pos_embed      = (const float*)d_in[5];
    const float* in_attn_norm_w = (const float*)d_in[6];
    const float* in_qkv_w       = (const float*)d_in[7];
    const float* in_out_w       = (const float*)d_in[8];
    const float* in_ff_norm_w   = (const float*)d_in[9];
    const float* in_w1          = (const float*)d_in[10];
    const float* in_w2          = (const float*)d_in[11];
    const float* mid_attn_norm_w= (const float*)d_in[12];
    const float* mid_qkv_w      = (const float*)d_in[13];
    const float* mid_out_w      = (const float*)d_in[14];
    const float* mid_ff_norm_w  = (const float*)d_in[15];
    const float* mid_w1         = (const float*)d_in[16];
    const float* mid_w2         = (const float*)d_in[17];
    const float* out_skip_w     = (const float*)d_in[18];
    const float* out_skip_b     = (const float*)d_in[19];
    const float* out_attn_norm_w= (const float*)d_in[20];
    const float* out_qkv_w      = (const float*)d_in[21];
    const float* out_out_w      = (const float*)d_in[22];
    const float* out_ff_norm_w  = (const float*)d_in[23];
    const float* out_w1         = (const float*)d_in[24];
    const float* out_w2         = (const float*)d_in[25];
    const float* final_norm_w   = (const float*)d_in[26];
    const float* ol_proj_w      = (const float*)d_in[27];
    const float* ol_proj_b      = (const float*)d_in[28];
    const float* rb_conv_in_w   = (const float*)d_in[29];
    const float* rb_gn_w        = (const float*)d_in[30];
    const float* rb_gn_b        = (const float*)d_in[31];
    const float* rb_conv1_w     = (const float*)d_in[32];
    const float* rb_conv2_w     = (const float*)d_in[33];
    const float* head_conv_w    = (const float*)d_in[34];

    WsMap W;
    float* f = (float*)d_ws;
    const size_t TD = (size_t)M_*D_;
    W.t      = f;               f += TD;
    W.skip   = f;               f += TD;
    W.t2     = f;               f += TD;
    W.ybuf   = f;               f += TD;
    W.img    = f;               f += TD;
    W.partial= f;               f += 131072;
    W.hpart  = f;               f += (size_t)8*4*IMG_*IMG_;
    W.stats  = f;               f += 448;
    W.part   = f;               f += (size_t)4*TD;
    ushort_t* u = (ushort_t*)f;
    W.nb     = u;               u += TD;
    W.qkvb   = u;               u += (size_t)M_*3*D_;
    W.ab     = u;               u += TD;
    W.gbuf   = u;               u += (size_t)M_*FF_;
    W.cat    = u;               u += (size_t)M_*2*D_;
    W.wb_qkv = u;               u += (size_t)10*D_*3*D_;
    W.wb_out = u;               u += (size_t)10*D_*D_;
    W.wb_w1  = u;               u += (size_t)10*D_*2*FF_;
    W.wb_w2  = u;               u += (size_t)10*FF_*D_;
    W.wb_pe  = u;               u += (size_t)D_*D_;
    W.wb_skip= u;               u += (size_t)2*D_*D_;
    W.wb_ol  = u;               u += (size_t)D_*D_;
    W.cA     = u;               u += (size_t)NCONV_;
    W.cB     = u;

    float* st0 = W.stats;       float* st1 = W.stats + 64;
    float* st2 = W.stats + 128; float* st3 = W.stats + 192;
    float* st4 = W.stats + 256;

    // --- weight convert+transpose (bf16, [N][K])
    k_wt<<<dim3(3*D_/32, D_/32, 10), 256, 0, stream>>>(in_qkv_w, mid_qkv_w, out_qkv_w, 6, 3, W.wb_qkv, D_, 3*D_);
    k_wt<<<dim3(D_/32, D_/32, 10), 256, 0, stream>>>(in_out_w, mid_out_w, out_out_w, 6, 3, W.wb_out, D_, D_);
    k_wt<<<dim3(2*FF_/32, D_/32, 10), 256, 0, stream>>>(in_w1, mid_w1, out_w1, 6, 3, W.wb_w1, D_, 2*FF_);
    k_wt<<<dim3(D_/32, FF_/32, 10), 256, 0, stream>>>(in_w2, mid_w2, out_w2, 6, 3, W.wb_w2, FF_, D_);
    k_wt<<<dim3(D_/32, D_/32, 1), 256, 0, stream>>>(pe_proj_w, nullptr, nullptr, 1, 0, W.wb_pe, D_, D_);
    k_wt<<<dim3(D_/32, 2*D_/32, 1), 256, 0, stream>>>(out_skip_w, nullptr, nullptr, 1, 0, W.wb_skip, 2*D_, D_);
    k_wt<<<dim3(D_/32, D_/32, 1), 256, 0, stream>>>(ol_proj_w, nullptr, nullptr, 1, 0, W.wb_ol, D_, D_);

    // --- patch embed
    k_patchify<<<(B_*L_*PD_)/256, 256, 0, stream>>>(x, W.t2);
    k_rms<true><<<M_, 256, 0, stream>>>(W.t2, pe_norm_w, nullptr, W.nb);
    k_gemm<false,1><<<dim3(D_/64, M_/64), 256, 0, stream>>>(W.nb, W.wb_pe, W.t, pe_proj_b, nullptr, D_, D_);
    k_rms<false><<<M_, 256, 0, stream>>>(W.t, pe_norm_out_w, pos_embed, W.t);
    k_rms<true><<<M_, 256, 0, stream>>>(W.t, in_attn_norm_w, nullptr, W.nb);   // prime block 0

    // --- 6 in blocks (nb chained via k_skred_rms)
    for (int i = 0; i < 6; ++i){
        const float* next_w = (i < 5) ? in_attn_norm_w + (size_t)(i+1)*D_ : mid_attn_norm_w;
        run_block(in_ff_norm_w + (size_t)i*D_, W.wb_qkv + (size_t)i*D_*3*D_,
                  W.wb_out + (size_t)i*D_*D_,
                  W.wb_w1 + (size_t)i*D_*2*FF_, W.wb_w2 + (size_t)i*FF_*D_,
                  next_w, W.t, W, stream);
    }
    hipMemcpyAsync(W.skip, W.t, TD*sizeof(float), hipMemcpyDeviceToDevice, stream);

    // --- 3 middle blocks
    for (int i = 0; i < 3; ++i){
        int z = 6 + i;
        const float* next_w = (i < 2) ? mid_attn_norm_w + (size_t)(i+1)*D_ : nullptr;
        run_block(mid_ff_norm_w + (size_t)i*D_, W.wb_qkv + (size_t)z*D_*3*D_,
                  W.wb_out + (size_t)z*D_*D_,
                  W.wb_w1 + (size_t)z*D_*2*FF_, W.wb_w2 + (size_t)z*FF_*D_,
                  next_w, W.t, W, stream);
    }

    // --- skip concat projection
    k_cat<<<(M_*D_)/1024, 256, 0, stream>>>(W.t, W.skip, W.cat);
    k_gemm<false,1><<<dim3(D_/64, M_/64), 256, 0, stream>>>(W.cat, W.wb_skip, W.t2, out_skip_b, nullptr, D_, 2*D_);

    // --- out block (prime nb, chain to final norm)
    k_rms<true><<<M_, 256, 0, stream>>>(W.t2, out_attn_norm_w, nullptr, W.nb);
    run_block(out_ff_norm_w, W.wb_qkv + (size_t)9*D_*3*D_, W.wb_out + (size_t)9*D_*D_,
              W.wb_w1 + (size_t)9*D_*2*FF_, W.wb_w2 + (size_t)9*FF_*D_,
              final_norm_w, W.t2, W, stream);

    // --- out proj (nb = rms(t2, final_norm_w)) + unpatchify
    k_gemm<false,1><<<dim3(PD_/64, M_/64), 256, 0, stream>>>(W.nb, W.wb_ol, W.ybuf, ol_proj_b, nullptr, PD_, D_);
    k_unpatchify<<<(B_*3*IMG_*IMG_)/256, 256, 0, stream>>>(W.ybuf, W.img);

    // --- ResNet head (measured-best config: materialized act, pure-conv dw)
    k_conv_in<<<dim3(256, 4, 4), 256, 0, stream>>>(W.img, rb_conv_in_w, W.cA, W.partial);
    k_gn_fin<<<32, 256, 0, stream>>>(W.partial, 256, st0);
    k_act<<<8192, 256, 0, stream>>>(W.cA, st0, rb_gn_w, rb_gn_b, W.cB);
    k_dw<2,1><<<dim3(32, 128, 4), 256, 0, stream>>>(W.cB, rb_conv1_w, W.cA, W.partial);
    k_gn_fin<<<32, 256, 0, stream>>>(W.partial, 512, st1);
    k_addmish<<<8192, 256, 0, stream>>>(W.cA, st1, rb_gn_w+128, rb_gn_b+128, W.cB, W.cA, W.partial);
    k_gn_fin<<<32, 256, 0, stream>>>(W.partial, 256, st2);
    k_act<<<8192, 256, 0, stream>>>(W.cA, st2, rb_gn_w+256, rb_gn_b+256, W.cB);
    k_dw<6,3><<<dim3(32, 128, 4), 256, 0, stream>>>(W.cB, rb_conv2_w, W.cA, W.partial);
    k_gn_fin<<<32, 256, 0, stream>>>(W.partial, 512, st3);
    k_addmish<<<8192, 256, 0, stream>>>(W.cA, st3, rb_gn_w+384, rb_gn_b+384, W.cB, W.cA, W.partial);
    k_gn_fin<<<32, 256, 0, stream>>>(W.partial, 256, st4);
    k_head_part<<<dim3(64, 8, 4), 256, 0, stream>>>(W.cA, st4, rb_gn_w+512, rb_gn_b+512, head_conv_w, W.hpart);
    k_head_fin<<<(B_*IMG_*IMG_)/1024, 256, 0, stream>>>(W.hpart, (float*)d_out);
}

// Round 15
// 1416.365 us; speedup vs baseline: 1.0233x; 1.0233x over previous
//
#include <hip/hip_runtime.h>
#include <math.h>

#define B_ 4
#define D_ 768
#define NH_ 12
#define HD_ 64
#define FF_ 3072
#define L_ 256
#define PD_ 768
#define GRID_ 16
#define P_ 16
#define IMG_ 256
#define M_ (B_*L_)                 // 1024 rows
#define NCONV_ (B_*128*IMG_*IMG_)  // 33554432

typedef __attribute__((ext_vector_type(8))) short short8;
typedef __attribute__((ext_vector_type(4))) float f32x4;
typedef __attribute__((ext_vector_type(4))) unsigned short us4;
typedef __attribute__((ext_vector_type(8))) unsigned short us8;
typedef unsigned short ushort_t;

__device__ __forceinline__ float mishf(float x){
    float e = __expf(x);
    float u = (1.f + e) * (1.f + e);
    return x * (1.f - 2.f / (u + 1.f));
}

__device__ __forceinline__ int refl(int i, int n){
    if (i < 0) i = -i;
    if (i >= n) i = 2*n - 2 - i;
    return i;
}

__device__ __forceinline__ ushort_t f2bf(float f){
    unsigned int u = __float_as_uint(f);
    unsigned int r = (u + 0x7FFFu + ((u >> 16) & 1u)) >> 16;
    return (ushort_t)r;
}
__device__ __forceinline__ float bf2f(ushort_t u){
    return __uint_as_float(((unsigned int)u) << 16);
}

// async global->LDS, 16B per lane; lds dest must be wave-uniform (HW adds lane*16)
__device__ __forceinline__ void gl16(const void* g, void* l){
    __builtin_amdgcn_global_load_lds(
        (const __attribute__((address_space(1))) unsigned int*)g,
        (__attribute__((address_space(3))) unsigned int*)l, 16, 0, 0);
}

__device__ __forceinline__ void block_red2(float& s, float& q){
    #pragma unroll
    for (int o = 32; o > 0; o >>= 1){ s += __shfl_down(s, o); q += __shfl_down(q, o); }
    __shared__ float r1[4], r2[4];
    int tid = threadIdx.x;
    if ((tid & 63) == 0){ r1[tid>>6] = s; r2[tid>>6] = q; }
    __syncthreads();
    if (tid == 0){ s = r1[0]+r1[1]+r1[2]+r1[3]; q = r2[0]+r2[1]+r2[2]+r2[3]; }
    __syncthreads();
}

// ---------------- patchify
__global__ __launch_bounds__(256) void k_patchify(const float* __restrict__ x, float* __restrict__ t){
    int idx = blockIdx.x*256 + threadIdx.x;
    int d = idx % PD_; int l = (idx/PD_) % L_; int b = idx/(PD_*L_);
    int c = d % 3; int p = d / 3; int p1 = p / P_; int p2 = p % P_;
    int gh = l / GRID_; int gw = l % GRID_;
    int sy = gh*P_ + p1, sx = gw*P_ + p2;
    t[idx] = x[(((size_t)b*3 + c)*IMG_ + sy)*IMG_ + sx];
}

// ---------------- weight transpose+convert: W[K][N] f32 -> Wt[N][K] bf16
__global__ __launch_bounds__(256) void k_wt(const float* __restrict__ b0, const float* __restrict__ b1,
                                            const float* __restrict__ b2, int n0, int n1,
                                            ushort_t* __restrict__ dst, int K, int N){
    int z = blockIdx.z;
    size_t sz = (size_t)K * N;
    const float* src = (z < n0) ? b0 + (size_t)z*sz
                     : (z < n0+n1) ? b1 + (size_t)(z-n0)*sz
                     : b2 + (size_t)(z-n0-n1)*sz;
    ushort_t* out = dst + (size_t)z*sz;
    __shared__ float ld[32][33];
    int k0 = blockIdx.y*32, nc0 = blockIdx.x*32;
    int tid = threadIdx.x;
    int c = tid & 31, r8 = tid >> 5;
    #pragma unroll
    for (int i = 0; i < 4; ++i){
        int k = r8 + i*8;
        ld[k][c] = src[(size_t)(k0+k)*N + nc0 + c];
    }
    __syncthreads();
    #pragma unroll
    for (int i = 0; i < 4; ++i){
        int n = r8 + i*8;
        out[(size_t)(nc0+n)*K + k0 + c] = f2bf(ld[c][n]);
    }
}

// ---------------- RMSNorm
template<bool OUT_BF>
__global__ __launch_bounds__(256) void k_rms(const float* __restrict__ x, const float* __restrict__ w,
                                             const float* __restrict__ addv, void* __restrict__ yv){
    int row = blockIdx.x;
    const float* xr = x + (size_t)row * D_;
    float s = 0.f;
    for (int i = threadIdx.x; i < D_; i += 256){ float v = xr[i]; s += v*v; }
    __shared__ float red[256];
    red[threadIdx.x] = s; __syncthreads();
    for (int o = 128; o > 0; o >>= 1){
        if (threadIdx.x < o) red[threadIdx.x] += red[threadIdx.x+o];
        __syncthreads();
    }
    float rstd = rsqrtf(red[0]/(float)D_ + 1e-5f);
    int l = row % L_;
    for (int i = threadIdx.x; i < D_; i += 256){
        float v = xr[i]*rstd*w[i];
        if (addv) v += addv[(size_t)l*D_ + i];
        if (OUT_BF) ((ushort_t*)yv)[(size_t)row*D_ + i] = f2bf(v);
        else        ((float*)yv)[(size_t)row*D_ + i] = v;
    }
}

// ---------------- fused split-K(2) reduce + residual + (optional) next RMSNorm
__global__ __launch_bounds__(256) void k_skred_rms(const float* __restrict__ Pp, float* __restrict__ t,
                                                   const float* __restrict__ w, ushort_t* __restrict__ nb){
    int row = blockIdx.x;
    int tid = threadIdx.x;
    float v[3];
    float s = 0.f;
    #pragma unroll
    for (int i = 0; i < 3; ++i){
        int c = tid + i*256;
        size_t o = (size_t)row*D_ + c;
        float x = t[o] + Pp[o] + Pp[(size_t)M_*D_ + o];
        v[i] = x; s += x*x;
        t[o] = x;
    }
    #pragma unroll
    for (int o = 32; o > 0; o >>= 1) s += __shfl_down(s, o);
    __shared__ float r1[4];
    if ((tid & 63) == 0) r1[tid>>6] = s;
    __syncthreads();
    float tot = r1[0]+r1[1]+r1[2]+r1[3];
    float rstd = rsqrtf(tot*(1.f/768.f) + 1e-5f);
    if (w){
        #pragma unroll
        for (int i = 0; i < 3; ++i){
            int c = tid + i*256;
            nb[(size_t)row*D_ + c] = f2bf(v[i]*rstd*w[c]);
        }
    }
}

// ---------------- bf16 MFMA GEMM 64x64, BK=64, global_load_lds staging (R13 measured-best).
// LDS [64][32] unpadded: fragment reads sweep 1KB/wave contiguous (conflict-free);
// staging: lane l of wave w feeds row w*16 + l/4, col (l%4)*8 (matches HW lane*16 layout).
template<bool OBF, int SPLITK>
__global__ __launch_bounds__(256) void k_gemm(const ushort_t* __restrict__ A, const ushort_t* __restrict__ Wt,
                                              void* __restrict__ Cv, const float* __restrict__ bias,
                                              const float* __restrict__ res, int N, int K){
    __shared__ ushort_t As[2][64][32];
    __shared__ ushort_t Ws[2][64][32];
    int tid = threadIdx.x;
    int lane = tid & 63, wid = tid >> 6;
    int wr = wid >> 1, wc = wid & 1;
    int row0 = blockIdx.y * 64, col0 = blockIdx.x * 64;
    f32x4 acc[2][2];
    #pragma unroll
    for (int i = 0; i < 2; ++i)
        #pragma unroll
        for (int j = 0; j < 2; ++j) acc[i][j] = (f32x4){0.f,0.f,0.f,0.f};

    int lg = lane >> 4, lr = lane & 15;
    int kc = K / SPLITK;
    int k0 = (SPLITK > 1) ? blockIdx.z * kc : 0;
    int srow = wid*16 + (lane >> 2);
    int scol = (lane & 3) * 8;
    const ushort_t* gA = A  + (size_t)(row0 + srow)*K + k0 + scol;
    const ushort_t* gW = Wt + (size_t)(col0 + srow)*K + k0 + scol;
    ushort_t* lA0 = &As[0][wid*16][0];
    ushort_t* lA1 = &As[1][wid*16][0];
    ushort_t* lW0 = &Ws[0][wid*16][0];
    ushort_t* lW1 = &Ws[1][wid*16][0];

    for (int kt = 0; kt < kc; kt += 64){
        __syncthreads();
        gl16(gA + kt,      lA0);
        gl16(gA + kt + 32, lA1);
        gl16(gW + kt,      lW0);
        gl16(gW + kt + 32, lW1);
        __syncthreads();
        short8 a0[2], a1[2], b0[2], b1[2];
        #pragma unroll
        for (int i = 0; i < 2; ++i){
            a0[i] = *(const short8*)(&As[0][wr*32 + i*16 + lr][lg*8]);
            a1[i] = *(const short8*)(&As[1][wr*32 + i*16 + lr][lg*8]);
        }
        #pragma unroll
        for (int j = 0; j < 2; ++j){
            b0[j] = *(const short8*)(&Ws[0][wc*32 + j*16 + lr][lg*8]);
            b1[j] = *(const short8*)(&Ws[1][wc*32 + j*16 + lr][lg*8]);
        }
        #pragma unroll
        for (int i = 0; i < 2; ++i)
            #pragma unroll
            for (int j = 0; j < 2; ++j){
                acc[i][j] = __builtin_amdgcn_mfma_f32_16x16x32_bf16(a0[i], b0[j], acc[i][j], 0, 0, 0);
                acc[i][j] = __builtin_amdgcn_mfma_f32_16x16x32_bf16(a1[i], b1[j], acc[i][j], 0, 0, 0);
            }
    }
    if (SPLITK > 1){
        float* Pp = (float*)Cv + (size_t)blockIdx.z * M_ * N;
        #pragma unroll
        for (int i = 0; i < 2; ++i)
            #pragma unroll
            for (int j = 0; j < 2; ++j)
                #pragma unroll
                for (int q = 0; q < 4; ++q){
                    int m = row0 + wr*32 + i*16 + lg*4 + q;
                    int n = col0 + wc*32 + j*16 + lr;
                    Pp[(size_t)m*N + n] = acc[i][j][q];
                }
    } else {
        #pragma unroll
        for (int i = 0; i < 2; ++i)
            #pragma unroll
            for (int j = 0; j < 2; ++j)
                #pragma unroll
                for (int q = 0; q < 4; ++q){
                    int m = row0 + wr*32 + i*16 + lg*4 + q;
                    int n = col0 + wc*32 + j*16 + lr;
                    float v = acc[i][j][q];
                    if (bias) v += bias[n];
                    size_t o = (size_t)m*N + n;
                    if (OBF){
                        ((ushort_t*)Cv)[o] = f2bf(v);
                    } else {
                        if (res) v += res[o];
                        ((float*)Cv)[o] = v;
                    }
                }
    }
}

// ---------------- ff1 GEMM with fused mish-GLU epilogue, BK=64, global_load_lds staging.
__global__ __launch_bounds__(256) void k_gemm_glu(const ushort_t* __restrict__ A, const ushort_t* __restrict__ Wt,
                                                  ushort_t* __restrict__ Cb, int K){
    __shared__ ushort_t As[2][64][32];
    __shared__ ushort_t Wa[2][64][32];
    __shared__ ushort_t Wg[2][64][32];
    int tid = threadIdx.x;
    int lane = tid & 63, wid = tid >> 6;
    int wr = wid >> 1, wc = wid & 1;
    int row0 = blockIdx.y * 64, col0 = blockIdx.x * 64;
    f32x4 aa[2][2], ag[2][2];
    #pragma unroll
    for (int i = 0; i < 2; ++i)
        #pragma unroll
        for (int j = 0; j < 2; ++j){ aa[i][j] = (f32x4){0.f,0.f,0.f,0.f}; ag[i][j] = (f32x4){0.f,0.f,0.f,0.f}; }

    int lg = lane >> 4, lr = lane & 15;
    int srow = wid*16 + (lane >> 2);
    int scol = (lane & 3) * 8;
    const ushort_t* gA  = A  + (size_t)(row0 + srow)*K + scol;
    const ushort_t* gWa = Wt + (size_t)(col0 + srow)*K + scol;
    const ushort_t* gWg = Wt + (size_t)(FF_ + col0 + srow)*K + scol;
    ushort_t* lA0 = &As[0][wid*16][0];  ushort_t* lA1 = &As[1][wid*16][0];
    ushort_t* la0 = &Wa[0][wid*16][0];  ushort_t* la1 = &Wa[1][wid*16][0];
    ushort_t* lg0 = &Wg[0][wid*16][0];  ushort_t* lg1 = &Wg[1][wid*16][0];

    for (int kt = 0; kt < K; kt += 64){
        __syncthreads();
        gl16(gA  + kt,      lA0);
        gl16(gA  + kt + 32, lA1);
        gl16(gWa + kt,      la0);
        gl16(gWa + kt + 32, la1);
        gl16(gWg + kt,      lg0);
        gl16(gWg + kt + 32, lg1);
        __syncthreads();
        short8 a0[2], a1[2], ba0[2], ba1[2], bg0[2], bg1[2];
        #pragma unroll
        for (int i = 0; i < 2; ++i){
            a0[i] = *(const short8*)(&As[0][wr*32 + i*16 + lr][lg*8]);
            a1[i] = *(const short8*)(&As[1][wr*32 + i*16 + lr][lg*8]);
        }
        #pragma unroll
        for (int j = 0; j < 2; ++j){
            ba0[j] = *(const short8*)(&Wa[0][wc*32 + j*16 + lr][lg*8]);
            ba1[j] = *(const short8*)(&Wa[1][wc*32 + j*16 + lr][lg*8]);
            bg0[j] = *(const short8*)(&Wg[0][wc*32 + j*16 + lr][lg*8]);
            bg1[j] = *(const short8*)(&Wg[1][wc*32 + j*16 + lr][lg*8]);
        }
        #pragma unroll
        for (int i = 0; i < 2; ++i)
            #pragma unroll
            for (int j = 0; j < 2; ++j){
                aa[i][j] = __builtin_amdgcn_mfma_f32_16x16x32_bf16(a0[i], ba0[j], aa[i][j], 0, 0, 0);
                aa[i][j] = __builtin_amdgcn_mfma_f32_16x16x32_bf16(a1[i], ba1[j], aa[i][j], 0, 0, 0);
                ag[i][j] = __builtin_amdgcn_mfma_f32_16x16x32_bf16(a0[i], bg0[j], ag[i][j], 0, 0, 0);
                ag[i][j] = __builtin_amdgcn_mfma_f32_16x16x32_bf16(a1[i], bg1[j], ag[i][j], 0, 0, 0);
            }
    }
    #pragma unroll
    for (int i = 0; i < 2; ++i)
        #pragma unroll
        for (int j = 0; j < 2; ++j)
            #pragma unroll
            for (int q = 0; q < 4; ++q){
                int m = row0 + wr*32 + i*16 + lg*4 + q;
                int n = col0 + wc*32 + j*16 + lr;
                Cb[(size_t)m*FF_ + n] = f2bf(mishf(aa[i][j][q]) * ag[i][j][q]);
            }
}

// ---------------- MFMA attention (unchanged, verified)
__global__ __launch_bounds__(256) void k_attn(const ushort_t* __restrict__ qkv, ushort_t* __restrict__ out){
    int qt = blockIdx.x, h = blockIdx.y, b = blockIdx.z;
    const ushort_t* base = qkv + (size_t)b * L_ * 3 * D_;
    __shared__ ushort_t Qs[64][72];
    __shared__ ushort_t KVs[64][72];
    __shared__ ushort_t Ps[64][268];
    __shared__ float red[8][64];
    int tid = threadIdx.x;
    int lane = tid & 63, w = tid >> 6;
    int lr = lane & 15, lg = lane >> 4;

    {
        int r = tid >> 2, c = (tid & 3) * 16;
        const ushort_t* src = base + (size_t)(qt*64 + r)*3*D_ + h*HD_ + c;
        *(us8*)&Qs[r][c]   = *(const us8*)src;
        *(us8*)&Qs[r][c+8] = *(const us8*)(src + 8);
    }

    f32x4 sacc[4][4];
    #pragma unroll
    for (int kt = 0; kt < 4; ++kt)
        #pragma unroll
        for (int mi = 0; mi < 4; ++mi) sacc[kt][mi] = (f32x4){0.f,0.f,0.f,0.f};

    for (int kt = 0; kt < 4; ++kt){
        __syncthreads();
        {
            int r = tid >> 2, c = (tid & 3) * 16;
            const ushort_t* src = base + (size_t)(kt*64 + r)*3*D_ + D_ + h*HD_ + c;
            *(us8*)&KVs[r][c]   = *(const us8*)src;
            *(us8*)&KVs[r][c+8] = *(const us8*)(src + 8);
        }
        __syncthreads();
        short8 bk0 = *(const short8*)&KVs[w*16 + lr][lg*8];
        short8 bk1 = *(const short8*)&KVs[w*16 + lr][32 + lg*8];
        #pragma unroll
        for (int mi = 0; mi < 4; ++mi){
            short8 a0 = *(const short8*)&Qs[mi*16 + lr][lg*8];
            short8 a1 = *(const short8*)&Qs[mi*16 + lr][32 + lg*8];
            sacc[kt][mi] = __builtin_amdgcn_mfma_f32_16x16x32_bf16(a0, bk0, sacc[kt][mi], 0, 0, 0);
            sacc[kt][mi] = __builtin_amdgcn_mfma_f32_16x16x32_bf16(a1, bk1, sacc[kt][mi], 0, 0, 0);
        }
    }

    const float inv64 = 1.0f/64.0f;
    float gm[4][4], linv[4][4];
    #pragma unroll
    for (int mi = 0; mi < 4; ++mi){
        #pragma unroll
        for (int r = 0; r < 4; ++r){
            float v = fmaxf(fmaxf(sacc[0][mi][r], sacc[1][mi][r]), fmaxf(sacc[2][mi][r], sacc[3][mi][r]));
            v = fmaxf(v, __shfl_xor(v, 1));
            v = fmaxf(v, __shfl_xor(v, 2));
            v = fmaxf(v, __shfl_xor(v, 4));
            v = fmaxf(v, __shfl_xor(v, 8));
            gm[mi][r] = v;
            if (lr == 0) red[w][mi*16 + lg*4 + r] = v;
        }
    }
    __syncthreads();
    #pragma unroll
    for (int mi = 0; mi < 4; ++mi){
        #pragma unroll
        for (int r = 0; r < 4; ++r){
            int row = mi*16 + lg*4 + r;
            float m = fmaxf(fmaxf(red[0][row], red[1][row]), fmaxf(red[2][row], red[3][row]));
            gm[mi][r] = m;
            float sum = 0.f;
            #pragma unroll
            for (int kt = 0; kt < 4; ++kt){
                float p = __expf((sacc[kt][mi][r] - m) * inv64);
                Ps[row][kt*64 + w*16 + lr] = f2bf(p);
                sum += p;
            }
            sum += __shfl_xor(sum, 1);
            sum += __shfl_xor(sum, 2);
            sum += __shfl_xor(sum, 4);
            sum += __shfl_xor(sum, 8);
            linv[mi][r] = sum;
            if (lr == 0) red[4 + w][row] = sum;
        }
    }
    __syncthreads();
    #pragma unroll
    for (int mi = 0; mi < 4; ++mi){
        #pragma unroll
        for (int r = 0; r < 4; ++r){
            int row = mi*16 + lg*4 + r;
            linv[mi][r] = 1.0f / (red[4][row] + red[5][row] + red[6][row] + red[7][row]);
        }
    }

    f32x4 oacc[4];
    #pragma unroll
    for (int mi = 0; mi < 4; ++mi) oacc[mi] = (f32x4){0.f,0.f,0.f,0.f};
    for (int kt = 0; kt < 4; ++kt){
        __syncthreads();
        {
            int k = tid & 63, dg = tid >> 6;
            const ushort_t* src = base + (size_t)(kt*64 + k)*3*D_ + 2*D_ + h*HD_ + dg*16;
            us8 v0 = *(const us8*)src;
            us8 v1 = *(const us8*)(src + 8);
            #pragma unroll
            for (int j = 0; j < 8; ++j) KVs[dg*16 + j][k] = v0[j];
            #pragma unroll
            for (int j = 0; j < 8; ++j) KVs[dg*16 + 8 + j][k] = v1[j];
        }
        __syncthreads();
        short8 bv0 = *(const short8*)&KVs[w*16 + lr][lg*8];
        short8 bv1 = *(const short8*)&KVs[w*16 + lr][32 + lg*8];
        #pragma unroll
        for (int mi = 0; mi < 4; ++mi){
            short8 a0 = *(const short8*)&Ps[mi*16 + lr][kt*64 + lg*8];
            short8 a1 = *(const short8*)&Ps[mi*16 + lr][kt*64 + 32 + lg*8];
            oacc[mi] = __builtin_amdgcn_mfma_f32_16x16x32_bf16(a0, bv0, oacc[mi], 0, 0, 0);
            oacc[mi] = __builtin_amdgcn_mfma_f32_16x16x32_bf16(a1, bv1, oacc[mi], 0, 0, 0);
        }
    }
    #pragma unroll
    for (int mi = 0; mi < 4; ++mi){
        #pragma unroll
        for (int r = 0; r < 4; ++r){
            int row = mi*16 + lg*4 + r;
            out[((size_t)(b*L_ + qt*64 + row))*D_ + h*HD_ + w*16 + lr] = f2bf(oacc[mi][r] * linv[mi][r]);
        }
    }
}

// ---------------- concat convert
__global__ __launch_bounds__(256) void k_cat(const float* __restrict__ t, const float* __restrict__ skip,
                                             ushort_t* __restrict__ cat){
    int i4 = (blockIdx.x*256 + threadIdx.x) * 4;
    int r = i4 / D_, c = i4 % D_;
    float4 a = *(const float4*)(t + i4);
    float4 b = *(const float4*)(skip + i4);
    us4 ua, ub;
    ua.x=f2bf(a.x); ua.y=f2bf(a.y); ua.z=f2bf(a.z); ua.w=f2bf(a.w);
    ub.x=f2bf(b.x); ub.y=f2bf(b.y); ub.z=f2bf(b.z); ub.w=f2bf(b.w);
    *(us4*)(cat + (size_t)r*1536 + c) = ua;
    *(us4*)(cat + (size_t)r*1536 + 768 + c) = ub;
}

// ---------------- unpatchify
__global__ __launch_bounds__(256) void k_unpatchify(const float* __restrict__ t, float* __restrict__ img){
    int idx = blockIdx.x*256 + threadIdx.x;
    int sx = idx % IMG_; int sy = (idx/IMG_)%IMG_; int c = (idx/(IMG_*IMG_))%3; int b = idx/(3*IMG_*IMG_);
    int gh = sy / P_, p1 = sy % P_, gw = sx / P_, p2 = sx % P_;
    img[idx] = t[(((size_t)b*L_) + gh*GRID_+gw)*PD_ + (p1*P_+p2)*3 + c];
}

// ---------------- conv_in: 3->128, 3x3 reflect. block=(y, ocg, b); 32 oc per block.
__global__ __launch_bounds__(256) void k_conv_in(const float* __restrict__ img, const float* __restrict__ w,
                                                 ushort_t* __restrict__ out, float* __restrict__ partial){
    int y = blockIdx.x, ocg = blockIdx.y, b = blockIdx.z;
    int x = threadIdx.x;
    __shared__ float rows[9][IMG_];
    int yy0 = refl(y-1, IMG_), yy2 = refl(y+1, IMG_);
    #pragma unroll
    for (int ic = 0; ic < 3; ++ic){
        const float* basep = img + ((size_t)(b*3+ic))*IMG_*IMG_;
        rows[ic*3+0][x] = basep[(size_t)yy0*IMG_ + x];
        rows[ic*3+1][x] = basep[(size_t)y  *IMG_ + x];
        rows[ic*3+2][x] = basep[(size_t)yy2*IMG_ + x];
    }
    __syncthreads();
    int xl = (x==0)?1:x-1, xr = (x==255)?254:x+1;
    float sg = 0.f, qg = 0.f;
    for (int oc = ocg*32; oc < ocg*32 + 32; ++oc){
        const float* wv = w + oc*27;
        float acc = 0.f;
        #pragma unroll
        for (int ic = 0; ic < 3; ++ic){
            const float* wk = wv + ic*9;
            acc += rows[ic*3+0][xl]*wk[0] + rows[ic*3+0][x]*wk[1] + rows[ic*3+0][xr]*wk[2]
                 + rows[ic*3+1][xl]*wk[3] + rows[ic*3+1][x]*wk[4] + rows[ic*3+1][xr]*wk[5]
                 + rows[ic*3+2][xl]*wk[6] + rows[ic*3+2][x]*wk[7] + rows[ic*3+2][xr]*wk[8];
        }
        out[(((size_t)(b*128+oc))*IMG_ + y)*IMG_ + x] = f2bf(acc);
        sg += acc; qg += acc*acc;
        if ((oc & 15) == 15){
            block_red2(sg, qg);
            if (threadIdx.x == 0){
                int pidx = ((b*8 + (oc>>4))*256 + y);
                partial[pidx*2] = sg; partial[pidx*2+1] = qg;
            }
            sg = 0.f; qg = 0.f;
        }
    }
}

// ---------------- stats finish: 32 groups
__global__ __launch_bounds__(256) void k_gn_fin(const float* __restrict__ partial, int nper,
                                                float* __restrict__ stats){
    int bg = blockIdx.x, tid = threadIdx.x;
    float s = 0.f, q = 0.f;
    for (int i = tid; i < nper; i += 256){
        s += partial[((size_t)bg*nper + i)*2];
        q += partial[((size_t)bg*nper + i)*2 + 1];
    }
    block_red2(s, q);
    if (tid == 0){
        const float n = 16.f*IMG_*IMG_;
        float m = s/n;
        float var = q/n - m*m;
        stats[bg*2]   = m;
        stats[bg*2+1] = rsqrtf(var + 1e-5f);
    }
}

// ---------------- activation pass: y = mish(gn(x)) bf16
__global__ __launch_bounds__(256) void k_act(const ushort_t* __restrict__ x, const float* __restrict__ st,
                                             const float* __restrict__ gw, const float* __restrict__ gb,
                                             ushort_t* __restrict__ y){
    int bid = blockIdx.x;
    int b = bid >> 11, c = (bid >> 4) & 127;
    int bg = b*8 + (c>>4);
    float sc = st[bg*2+1]*gw[c], sb = gb[c] - st[bg*2]*sc;
    size_t e0 = (size_t)bid*4096 + threadIdx.x*16;
    us8 v0 = *(const us8*)(x + e0), v1 = *(const us8*)(x + e0 + 8);
    us8 r0, r1;
    #pragma unroll
    for (int i = 0; i < 8; ++i) r0[i] = f2bf(mishf(bf2f(v0[i])*sc + sb));
    #pragma unroll
    for (int i = 0; i < 8; ++i) r1[i] = f2bf(mishf(bf2f(v1[i])*sc + sb));
    *(us8*)(y + e0) = r0;
    *(us8*)(y + e0 + 8) = r1;
}

// ---------------- depthwise 5x5 pure conv (measured-best: strides 40/48, pre-activated input)
template<int PAD, int DIL>
__global__ __launch_bounds__(256) void k_dw(const ushort_t* __restrict__ in,
                                            const float* __restrict__ cw,
                                            ushort_t* __restrict__ out, float* __restrict__ partial){
    constexpr int AP = (DIL==1) ? 4 : 8;
    constexpr int SC = (DIL==1) ? 40 : 48;
    constexpr int SY = 64 + 2*PAD;
    constexpr int CH = SC/4;
    __shared__ float tile[SY*SC];
    int tileid = blockIdx.x, c = blockIdx.y, b = blockIdx.z;
    int x0 = (tileid & 7) * 32, y0 = (tileid >> 3) * 64;
    int tid = threadIdx.x;
    const ushort_t* ip = in + ((size_t)(b*128+c))*IMG_*IMG_;
    int xs = x0 - AP;
    if (xs >= 0 && xs + SC <= IMG_){
        for (int j = tid; j < SY*CH; j += 256){
            int r = j / CH, q = j - r*CH;
            int gy = refl(y0 - PAD + r, IMG_);
            us4 v = *(const us4*)(ip + (size_t)gy*IMG_ + xs + q*4);
            f32x4 fv = { bf2f(v.x), bf2f(v.y), bf2f(v.z), bf2f(v.w) };
            *(f32x4*)&tile[r*SC + q*4] = fv;
        }
    } else {
        for (int j = tid; j < SY*SC; j += 256){
            int r = j / SC, cc = j - r*SC;
            int gy = refl(y0 - PAD + r, IMG_);
            int gx = refl(xs + cc, IMG_);
            tile[r*SC + cc] = bf2f(ip[(size_t)gy*IMG_ + gx]);
        }
    }
    __syncthreads();
    float wreg[25];
    #pragma unroll
    for (int u = 0; u < 25; ++u) wreg[u] = cw[c*25 + u];
    int tx4 = (tid & 7)*4, ty = tid >> 3;
    constexpr int NV = (DIL==1) ? 3 : 5;
    float s = 0.f, q2 = 0.f;
    #pragma unroll
    for (int rr = 0; rr < 2; ++rr){
        int yy = ty + rr*32;
        float acc[4] = {0.f,0.f,0.f,0.f};
        #pragma unroll
        for (int kh = 0; kh < 5; ++kh){
            const float* rowp = &tile[(yy + kh*DIL)*SC + tx4];
            float vv[NV*4];
            #pragma unroll
            for (int u = 0; u < NV; ++u){
                f32x4 v = *(const f32x4*)(rowp + u*4);
                vv[u*4]=v.x; vv[u*4+1]=v.y; vv[u*4+2]=v.z; vv[u*4+3]=v.w;
            }
            #pragma unroll
            for (int kw = 0; kw < 5; ++kw){
                float wk = wreg[kh*5+kw];
                #pragma unroll
                for (int j = 0; j < 4; ++j)
                    acc[j] += vv[kw*DIL + j + (AP - 2*DIL)] * wk;
            }
        }
        us4 o4 = { f2bf(acc[0]), f2bf(acc[1]), f2bf(acc[2]), f2bf(acc[3]) };
        *(us4*)(out + (((size_t)(b*128+c))*IMG_ + y0+yy)*IMG_ + x0+tx4) = o4;
        s  += acc[0]+acc[1]+acc[2]+acc[3];
        q2 += acc[0]*acc[0]+acc[1]*acc[1]+acc[2]*acc[2]+acc[3]*acc[3];
    }
    block_red2(s, q2);
    if (tid == 0){
        int bid = (b*128 + c)*32 + tileid;
        partial[bid*2] = s; partial[bid*2+1] = q2;
    }
}

// ---------------- fused residual: out = mish(gn_n(xn)) + res_act (pre-activated residual)
__global__ __launch_bounds__(256) void k_addmish(const ushort_t* __restrict__ xn, const float* __restrict__ stn,
                                                 const float* __restrict__ wn, const float* __restrict__ bn,
                                                 const ushort_t* __restrict__ resa,
                                                 ushort_t* __restrict__ out, float* __restrict__ partial){
    int bid = blockIdx.x;
    int b = bid >> 11, c = (bid >> 4) & 127;
    int bg = b*8 + (c>>4);
    float scn = stn[bg*2+1]*wn[c], sbn = bn[c] - stn[bg*2]*scn;
    size_t e0 = (size_t)bid*4096 + threadIdx.x*16;
    us8 vn0 = *(const us8*)(xn + e0), vn1 = *(const us8*)(xn + e0 + 8);
    us8 vr0 = *(const us8*)(resa + e0), vr1 = *(const us8*)(resa + e0 + 8);
    us8 r0, r1;
    float s = 0.f, q = 0.f;
    #pragma unroll
    for (int i = 0; i < 8; ++i){
        float v = mishf(bf2f(vn0[i])*scn + sbn) + bf2f(vr0[i]);
        s += v; q += v*v; r0[i] = f2bf(v);
    }
    #pragma unroll
    for (int i = 0; i < 8; ++i){
        float v = mishf(bf2f(vn1[i])*scn + sbn) + bf2f(vr1[i]);
        s += v; q += v*v; r1[i] = f2bf(v);
    }
    *(us8*)(out + e0) = r0;
    *(us8*)(out + e0 + 8) = r1;
    block_red2(s, q);
    if (threadIdx.x == 0){ partial[bid*2] = s; partial[bid*2+1] = q; }
}

// ---------------- head conv part (unchanged)
__global__ __launch_bounds__(256) void k_head_part(const ushort_t* __restrict__ in, const float* __restrict__ st,
                                                   const float* __restrict__ gw, const float* __restrict__ gb,
                                                   const float* __restrict__ w, float* __restrict__ part){
    __shared__ float tile[34*34];
    int tileid = blockIdx.x, cg = blockIdx.y, b = blockIdx.z;
    int x0 = (tileid & 7)*32, y0 = (tileid >> 3)*32;
    int tid = threadIdx.x;
    int tx4 = (tid & 7)*4, ty = tid >> 3;
    float m  = st[(b*8+cg)*2];
    float rs = st[(b*8+cg)*2 + 1];
    float acc[4] = {0.f,0.f,0.f,0.f};
    for (int ci = 0; ci < 16; ++ci){
        int c = cg*16 + ci;
        float sc = rs*gw[c], sb = gb[c] - m*sc;
        const ushort_t* ip = in + ((size_t)(b*128+c))*IMG_*IMG_;
        if (ci) __syncthreads();
        for (int i = tid; i < 34*34; i += 256){
            int r = i/34, cc = i - r*34;
            int gy = refl(y0-1+r, IMG_);
            int gx = refl(x0-1+cc, IMG_);
            tile[i] = mishf(bf2f(ip[(size_t)gy*IMG_+gx])*sc + sb);
        }
        __syncthreads();
        const float* wc = w + c*9;
        #pragma unroll
        for (int kh = 0; kh < 3; ++kh){
            float vv[6];
            #pragma unroll
            for (int u = 0; u < 6; ++u) vv[u] = tile[(ty+kh)*34 + tx4 + u];
            #pragma unroll
            for (int kw = 0; kw < 3; ++kw){
                float wk = wc[kh*3+kw];
                #pragma unroll
                for (int j = 0; j < 4; ++j) acc[j] += vv[kw+j]*wk;
            }
        }
    }
    f32x4 o = {acc[0], acc[1], acc[2], acc[3]};
    *(f32x4*)(part + (((size_t)(cg*4+b))*IMG_ + y0+ty)*IMG_ + x0+tx4) = o;
}

__global__ __launch_bounds__(256) void k_head_fin(const float* __restrict__ part, float* __restrict__ out){
    int idx4 = blockIdx.x*256 + threadIdx.x;
    size_t e = (size_t)idx4*4;
    int b = (int)(e / (IMG_*IMG_));
    size_t off = e % (IMG_*IMG_);
    f32x4 s = {0.f,0.f,0.f,0.f};
    #pragma unroll
    for (int cg = 0; cg < 8; ++cg){
        f32x4 v = *(const f32x4*)(part + (size_t)(cg*4+b)*IMG_*IMG_ + off);
        s.x += v.x; s.y += v.y; s.z += v.z; s.w += v.w;
    }
    *(f32x4*)(out + e) = s;
}

// =======================================================================

struct WsMap {
    float *t, *skip, *t2, *ybuf, *img, *partial, *hpart, *stats, *part;
    ushort_t *nb, *qkvb, *ab, *gbuf, *cat, *wb_qkv, *wb_out, *wb_w1, *wb_w2, *wb_pe, *wb_skip, *wb_ol, *cA, *cB;
};

// Assumes W.nb already holds rms(t, this_attn_norm) bf16.
static void run_block(const float* fn, const ushort_t* qw, const ushort_t* ow,
                      const ushort_t* w1, const ushort_t* w2, const float* next_w,
                      float* t, const WsMap& W, hipStream_t stream){
    k_gemm<true,1><<<dim3(3*D_/64, M_/64), 256, 0, stream>>>(W.nb, qw, W.qkvb, nullptr, nullptr, 3*D_, D_);
    k_attn<<<dim3(4, NH_, B_), 256, 0, stream>>>(W.qkvb, W.ab);
    k_gemm<false,2><<<dim3(D_/64, M_/64, 2), 256, 0, stream>>>(W.ab, ow, W.part, nullptr, nullptr, D_, D_);
    k_skred_rms<<<M_, 256, 0, stream>>>(W.part, t, fn, W.nb);
    k_gemm_glu<<<dim3(FF_/64, M_/64), 256, 0, stream>>>(W.nb, w1, W.gbuf, D_);
    k_gemm<false,2><<<dim3(D_/64, M_/64, 2), 256, 0, stream>>>(W.gbuf, w2, W.part, nullptr, nullptr, D_, FF_);
    k_skred_rms<<<M_, 256, 0, stream>>>(W.part, t, next_w, W.nb);
}

extern "C" void kernel_launch(void* const* d_in, const int* in_sizes, int n_in,
                              void* d_out, int out_size, void* d_ws, size_t ws_size,
                              hipStream_t stream){
    const float* x              = (const float*)d_in[0];
    const float* pe_norm_w      = (const float*)d_in[1];
    const float* pe_proj_w      = (const float*)d_in[2];
    const float* pe_proj_b      = (const float*)d_in[3];
    const float* pe_norm_out_w  = (const float*)d_in[4];
    const float* pos_embed      = (const float*)d_in[5];
    const float* in_attn_norm_w = (const float*)d_in[6];
    const float* in_qkv_w       = (const float*)d_in[7];
    const float* in_out_w       = (const float*)d_in[8];
    const float* in_ff_norm_w   = (const float*)d_in[9];
    const float* in_w1          = (const float*)d_in[10];
    const float* in_w2          = (const float*)d_in[11];
    const float* mid_attn_norm_w= (const float*)d_in[12];
    const float* mid_qkv_w      = (const float*)d_in[13];
    const float* mid_out_w      = (const float*)d_in[14];
    const float* mid_ff_norm_w  = (const float*)d_in[15];
    const float* mid_w1         = (const float*)d_in[16];
    const float* mid_w2         = (const float*)d_in[17];
    const float* out_skip_w     = (const float*)d_in[18];
    const float* out_skip_b     = (const float*)d_in[19];
    const float* out_attn_norm_w= (const float*)d_in[20];
    const float* out_qkv_w      = (const float*)d_in[21];
    const float* out_out_w      = (const float*)d_in[22];
    const float* out_ff_norm_w  = (const float*)d_in[23];
    const float* out_w1         = (const float*)d_in[24];
    const float* out_w2         = (const float*)d_in[25];
    const float* final_norm_w   = (const float*)d_in[26];
    const float* ol_proj_w      = (const float*)d_in[27];
    const float* ol_proj_b      = (const float*)d_in[28];
    const float* rb_conv_in_w   = (const float*)d_in[29];
    const float* rb_gn_w        = (const float*)d_in[30];
    const float* rb_gn_b        = (const float*)d_in[31];
    const float* rb_conv1_w     = (const float*)d_in[32];
    const float* rb_conv2_w     = (const float*)d_in[33];
    const float* head_conv_w    = (const float*)d_in[34];

    WsMap W;
    float* f = (float*)d_ws;
    const size_t TD = (size_t)M_*D_;
    W.t      = f;               f += TD;
    W.skip   = f;               f += TD;
    W.t2     = f;               f += TD;
    W.ybuf   = f;               f += TD;
    W.img    = f;               f += TD;
    W.partial= f;               f += 131072;
    W.hpart  = f;               f += (size_t)8*4*IMG_*IMG_;
    W.stats  = f;               f += 448;
    W.part   = f;               f += (size_t)4*TD;
    ushort_t* u = (ushort_t*)f;
    W.nb     = u;               u += TD;
    W.qkvb   = u;               u += (size_t)M_*3*D_;
    W.ab     = u;               u += TD;
    W.gbuf   = u;               u += (size_t)M_*FF_;
    W.cat    = u;               u += (size_t)M_*2*D_;
    W.wb_qkv = u;               u += (size_t)10*D_*3*D_;
    W.wb_out = u;               u += (size_t)10*D_*D_;
    W.wb_w1  = u;               u += (size_t)10*D_*2*FF_;
    W.wb_w2  = u;               u += (size_t)10*FF_*D_;
    W.wb_pe  = u;               u += (size_t)D_*D_;
    W.wb_skip= u;               u += (size_t)2*D_*D_;
    W.wb_ol  = u;               u += (size_t)D_*D_;
    W.cA     = u;               u += (size_t)NCONV_;
    W.cB     = u;

    float* st0 = W.stats;       float* st1 = W.stats + 64;
    float* st2 = W.stats + 128; float* st3 = W.stats + 192;
    float* st4 = W.stats + 256;

    // --- weight convert+transpose (bf16, [N][K])
    k_wt<<<dim3(3*D_/32, D_/32, 10), 256, 0, stream>>>(in_qkv_w, mid_qkv_w, out_qkv_w, 6, 3, W.wb_qkv, D_, 3*D_);
    k_wt<<<dim3(D_/32, D_/32, 10), 256, 0, stream>>>(in_out_w, mid_out_w, out_out_w, 6, 3, W.wb_out, D_, D_);
    k_wt<<<dim3(2*FF_/32, D_/32, 10), 256, 0, stream>>>(in_w1, mid_w1, out_w1, 6, 3, W.wb_w1, D_, 2*FF_);
    k_wt<<<dim3(D_/32, FF_/32, 10), 256, 0, stream>>>(in_w2, mid_w2, out_w2, 6, 3, W.wb_w2, FF_, D_);
    k_wt<<<dim3(D_/32, D_/32, 1), 256, 0, stream>>>(pe_proj_w, nullptr, nullptr, 1, 0, W.wb_pe, D_, D_);
    k_wt<<<dim3(D_/32, 2*D_/32, 1), 256, 0, stream>>>(out_skip_w, nullptr, nullptr, 1, 0, W.wb_skip, 2*D_, D_);
    k_wt<<<dim3(D_/32, D_/32, 1), 256, 0, stream>>>(ol_proj_w, nullptr, nullptr, 1, 0, W.wb_ol, D_, D_);

    // --- patch embed
    k_patchify<<<(B_*L_*PD_)/256, 256, 0, stream>>>(x, W.t2);
    k_rms<true><<<M_, 256, 0, stream>>>(W.t2, pe_norm_w, nullptr, W.nb);
    k_gemm<false,1><<<dim3(D_/64, M_/64), 256, 0, stream>>>(W.nb, W.wb_pe, W.t, pe_proj_b, nullptr, D_, D_);
    k_rms<false><<<M_, 256, 0, stream>>>(W.t, pe_norm_out_w, pos_embed, W.t);
    k_rms<true><<<M_, 256, 0, stream>>>(W.t, in_attn_norm_w, nullptr, W.nb);   // prime block 0

    // --- 6 in blocks (nb chained via k_skred_rms)
    for (int i = 0; i < 6; ++i){
        const float* next_w = (i < 5) ? in_attn_norm_w + (size_t)(i+1)*D_ : mid_attn_norm_w;
        run_block(in_ff_norm_w + (size_t)i*D_, W.wb_qkv + (size_t)i*D_*3*D_,
                  W.wb_out + (size_t)i*D_*D_,
                  W.wb_w1 + (size_t)i*D_*2*FF_, W.wb_w2 + (size_t)i*FF_*D_,
                  next_w, W.t, W, stream);
    }
    hipMemcpyAsync(W.skip, W.t, TD*sizeof(float), hipMemcpyDeviceToDevice, stream);

    // --- 3 middle blocks
    for (int i = 0; i < 3; ++i){
        int z = 6 + i;
        const float* next_w = (i < 2) ? mid_attn_norm_w + (size_t)(i+1)*D_ : nullptr;
        run_block(mid_ff_norm_w + (size_t)i*D_, W.wb_qkv + (size_t)z*D_*3*D_,
                  W.wb_out + (size_t)z*D_*D_,
                  W.wb_w1 + (size_t)z*D_*2*FF_, W.wb_w2 + (size_t)z*FF_*D_,
                  next_w, W.t, W, stream);
    }

    // --- skip concat projection
    k_cat<<<(M_*D_)/1024, 256, 0, stream>>>(W.t, W.skip, W.cat);
    k_gemm<false,1><<<dim3(D_/64, M_/64), 256, 0, stream>>>(W.cat, W.wb_skip, W.t2, out_skip_b, nullptr, D_, 2*D_);

    // --- out block (prime nb, chain to final norm)
    k_rms<true><<<M_, 256, 0, stream>>>(W.t2, out_attn_norm_w, nullptr, W.nb);
    run_block(out_ff_norm_w, W.wb_qkv + (size_t)9*D_*3*D_, W.wb_out + (size_t)9*D_*D_,
              W.wb_w1 + (size_t)9*D_*2*FF_, W.wb_w2 + (size_t)9*FF_*D_,
              final_norm_w, W.t2, W, stream);

    // --- out proj (nb = rms(t2, final_norm_w)) + unpatchify
    k_gemm<false,1><<<dim3(PD_/64, M_/64), 256, 0, stream>>>(W.nb, W.wb_ol, W.ybuf, ol_proj_b, nullptr, PD_, D_);
    k_unpatchify<<<(B_*3*IMG_*IMG_)/256, 256, 0, stream>>>(W.ybuf, W.img);

    // --- ResNet head (measured-best config: materialized act, pure-conv dw)
    k_conv_in<<<dim3(256, 4, 4), 256, 0, stream>>>(W.img, rb_conv_in_w, W.cA, W.partial);
    k_gn_fin<<<32, 256, 0, stream>>>(W.partial, 256, st0);
    k_act<<<8192, 256, 0, stream>>>(W.cA, st0, rb_gn_w, rb_gn_b, W.cB);
    k_dw<2,1><<<dim3(32, 128, 4), 256, 0, stream>>>(W.cB, rb_conv1_w, W.cA, W.partial);
    k_gn_fin<<<32, 256, 0, stream>>>(W.partial, 512, st1);
    k_addmish<<<8192, 256, 0, stream>>>(W.cA, st1, rb_gn_w+128, rb_gn_b+128, W.cB, W.cA, W.partial);
    k_gn_fin<<<32, 256, 0, stream>>>(W.partial, 256, st2);
    k_act<<<8192, 256, 0, stream>>>(W.cA, st2, rb_gn_w+256, rb_gn_b+256, W.cB);
    k_dw<6,3><<<dim3(32, 128, 4), 256, 0, stream>>>(W.cB, rb_conv2_w, W.cA, W.partial);
    k_gn_fin<<<32, 256, 0, stream>>>(W.partial, 512, st3);
    k_addmish<<<8192, 256, 0, stream>>>(W.cA, st3, rb_gn_w+384, rb_gn_b+384, W.cB, W.cA, W.partial);
    k_gn_fin<<<32, 256, 0, stream>>>(W.partial, 256, st4);
    k_head_part<<<dim3(64, 8, 4), 256, 0, stream>>>(W.cA, st4, rb_gn_w+512, rb_gn_b+512, head_conv_w, W.hpart);
    k_head_fin<<<(B_*IMG_*IMG_)/1024, 256, 0, stream>>>(W.hpart, (float*)d_out);
}